// Round 4
// baseline (200.983 us; speedup 1.0000x reference)
//
#include <hip/hip_runtime.h>
#include <math.h>

// Problem constants
#define B_   32
#define L_   200
#define DIN_ 256
#define D_   64
#define PL_  8

// ws layout (float offsets)
#define OFF_WT    0         // 3*16384 transposed weights [i][d]
#define OFF_Q     49152     // B*L*D
#define OFF_NQ    458752
#define OFF_Z     868352
#define OFF_V     1277952
#define OFF_SZ    1687552   // B*L
#define OFF_SV    1693952
#define OFF_SNQ   1700352
#define OFF_PZL   1706752   // B*D
#define OFF_PSL   1708800   // B*D*D
#define OFF_PNAM  1839872   // B*D*D
#define OFF_MPS2  1970944   // B
#define OFF_H     1977376   // B*L diag terms
#define OFF_C     1983776   // B*L carr
#define OFF_CM    1990176   // B*L prefix of sz*sv
#define OFF_CR    1996576   // B*L prefix of 2*col-h
#define OFF_CCP   2002976   // B*L prefix of carr
#define OFF_SYR   2009376   // B*L row partial sums for std
#define OFF_SY2R  2015776   // B*L
#define OFF_ZC    2022176   // B*L*D cumsum of z
#define OFF_CP    2431776   // B*L*8 colsum partials per t-tile
#define OFF_T1    2482976   // B*L*D  NQ.PsL
#define OFF_T2    2892576   // B*L*D  NQ.pNAM
// end: 3302176 floats ~ 13.2 MB

__device__ __forceinline__ float wsum(float x){
#pragma unroll
  for (int o = 32; o > 0; o >>= 1) x += __shfl_xor(x, o, 64);
  return x;
}
__device__ __forceinline__ float eluf(float x){ return x > 0.f ? x : expm1f(x); }

// K0: transpose Wq,Wk,Wv [64,256] -> [256,64]
__global__ __launch_bounds__(256) void k_transpose(const float* __restrict__ Wq,
    const float* __restrict__ Wk, const float* __restrict__ Wv, float* __restrict__ wt){
  int idx = blockIdx.x*256 + threadIdx.x;
  if (idx >= 3*16384) return;
  int m = idx >> 14, r = idx & 16383, i = r >> 6, d = r & 63;
  const float* W = (m==0) ? Wq : ((m==1) ? Wk : Wv);
  wt[m*16384 + i*64 + d] = W[d*256 + i];
}

// K1: q,z,v GEMMs + per-row stats. 16 rows/block, 256 thr (wave g owns rows g+4j)
__global__ __launch_bounds__(256) void k_qzv(const float* __restrict__ x, const float* __restrict__ Wt,
    const float* __restrict__ bq, const float* __restrict__ bk, const float* __restrict__ bv,
    float* __restrict__ q, float* __restrict__ nq, float* __restrict__ z, float* __restrict__ v,
    float* __restrict__ sz, float* __restrict__ sv, float* __restrict__ snq){
  __shared__ float xs[16*256];
  int row0 = blockIdx.x * 16;
  int tid = threadIdx.x, d = tid & 63, g = tid >> 6;
  for (int k = tid; k < 4096; k += 256) xs[k] = x[row0*256 + k];
  __syncthreads();
  const float* Wtq = Wt;
  const float* Wtk = Wt + 16384;
  const float* Wtv = Wt + 32768;
  float aq[4] = {0,0,0,0}, ak[4] = {0,0,0,0}, av[4] = {0,0,0,0};
  for (int i = 0; i < 256; i++){
    float wq = Wtq[i*64+d], wk = Wtk[i*64+d], wv = Wtv[i*64+d];
#pragma unroll
    for (int j = 0; j < 4; j++){
      float xv = xs[(g+4*j)*256 + i];
      aq[j] = fmaf(xv, wq, aq[j]);
      ak[j] = fmaf(xv, wk, ak[j]);
      av[j] = fmaf(xv, wv, av[j]);
    }
  }
  float bqd = bq[d], bkd = bk[d], bvd = bv[d];
#pragma unroll
  for (int j = 0; j < 4; j++){
    int r = row0 + g + 4*j;
    float qv = eluf(aq[j] + bqd);
    float zv = eluf(ak[j] + bkd);
    float vv = av[j] + bvd;
    float sq2 = wsum(qv*qv);
    float sq1 = wsum(qv);
    float szv = wsum(zv);
    float svv = wsum(vv);
    float inv = 1.f / (sqrtf(sq2) + 1e-8f);
    q[r*64+d] = qv; nq[r*64+d] = qv*inv; z[r*64+d] = zv; v[r*64+d] = vv;
    if (d == 0){ sz[r] = szv; sv[r] = svv; snq[r] = sq1*inv; }
  }
}

// K2: prompt paths, split: block g: b = g&31, path = g>>5 (0: P -> PzL,PsL,mps2; 1: S -> pNAM)
__global__ __launch_bounds__(256) void k_prompt(const float* __restrict__ P, const float* __restrict__ Sp,
    const int* __restrict__ uid, const float* __restrict__ prev_z, const float* __restrict__ prev_s,
    const float* __restrict__ Wt, const float* __restrict__ bk, const float* __restrict__ bv,
    float* __restrict__ PzL, float* __restrict__ PsL, float* __restrict__ mps2, float* __restrict__ pNAM){
  int g = blockIdx.x, b = g & 31, path = g >> 5;
  int tid = threadIdx.x;
  __shared__ float xs[2048];
  __shared__ float zs[512], vs[512];
  __shared__ float red[4];
  __shared__ float facs;
  const float* src = path ? Sp : P;
  for (int k = tid; k < 2048; k += 256) xs[k] = src[b*2048 + k];
  __syncthreads();
  const float* Wtk = Wt + 16384;
  const float* Wtv = Wt + 32768;
  for (int idx = tid; idx < 512; idx += 256){
    int t = idx >> 6, d = idx & 63;
    float ak = 0.f, av = 0.f;
    for (int i = 0; i < 256; i++){
      float xv = xs[t*256+i];
      ak = fmaf(xv, Wtk[i*64+d], ak);
      av = fmaf(xv, Wtv[i*64+d], av);
    }
    zs[idx] = eluf(ak + bk[d]); vs[idx] = av + bv[d];
  }
  __syncthreads();
  // S_last = sum_t z v^T ; stats over 4096 entries
  float spv[16];
  float l1 = 0.f, l2 = 0.f;
  int p = tid >> 2, q0 = (tid & 3) * 16;
#pragma unroll
  for (int k = 0; k < 16; k++){
    int qq = q0 + k;
    float sp = 0.f;
#pragma unroll
    for (int t = 0; t < 8; t++) sp = fmaf(zs[t*64+p], vs[t*64+qq], sp);
    spv[k] = sp; l1 += sp; l2 += sp*sp;
  }
  float tot0, tot1;
  {
    float val = wsum(l1);
    if ((tid & 63) == 0) red[tid >> 6] = val;
    __syncthreads();
    tot0 = red[0] + red[1] + red[2] + red[3];
    __syncthreads();
    val = wsum(l2);
    if ((tid & 63) == 0) red[tid >> 6] = val;
    __syncthreads();
    tot1 = red[0] + red[1] + red[2] + red[3];
  }
  float mP = tot0 * (1.f/4096.f);
  float varP = tot1 * (1.f/4096.f) - mP*mP;
  float invv = rsqrtf(varP + 1e-5f);
  if (path == 0){
    if (tid == 0) mps2[b] = varP * invv * invv;  // E[PsL^2]
    if (tid < 64){
      int d = tid;
      float zc = 0.f;
#pragma unroll
      for (int t = 0; t < 8; t++) zc += zs[t*64+d];
      float s1 = wsum(zc), s2 = wsum(zc*zc);
      float mz = s1*(1.f/64.f), vz = s2*(1.f/64.f) - mz*mz;
      PzL[b*64+d] = (zc - mz) * rsqrtf(vz + 1e-5f);
    }
#pragma unroll
    for (int k = 0; k < 16; k++){
      int o = p*64 + q0 + k;
      PsL[b*4096 + o] = (spv[k] - mP) * invv;
    }
  } else {
    int u = uid[b];
    if (tid < 64){
      int d = tid;
      float zc = 0.f;
#pragma unroll
      for (int t = 0; t < 8; t++) zc += zs[t*64+d];
      float s1 = wsum(zc), s2 = wsum(zc*zc);
      float mz = s1*(1.f/64.f), vz = s2*(1.f/64.f) - mz*mz;
      float szl = (zc - mz) * rsqrtf(vz + 1e-5f);
      float pzv = prev_z[u*64 + d];
      float zu = pzv + szl;
      float zl2 = wsum(zu*zu);
      float psumv = wsum(pzv);
      float fac = ((psumv != 0.f) ? 1.f : 0.f) / (sqrtf(zl2) + 1e-8f);
      if (d == 0) facs = fac;
    }
    __syncthreads();
    float fac = facs;
    const float* psrow = prev_s + (size_t)u * 4096;
#pragma unroll
    for (int k = 0; k < 16; k++){
      int o = p*64 + q0 + k;
      pNAM[b*4096 + o] = (psrow[o] + (spv[k] - mP) * invv) * fac;
    }
  }
}

// K3a: tiled Gram: tile-pair (lt,tt<=lt): partial colsums + diag h.
// Diag blocks additionally: carr (z^T PsL v) and T1=NQ.PsL, T2=NQ.pNAM for their 32 rows.
#define PADK 68
__global__ __launch_bounds__(256) void k_gram_tile(const float* __restrict__ z, const float* __restrict__ v,
    const float* __restrict__ nq, const float* __restrict__ PsL, const float* __restrict__ pNAM,
    float* __restrict__ colpart, float* __restrict__ harr, float* __restrict__ carr,
    float* __restrict__ T1, float* __restrict__ T2){
  int b = blockIdx.x / 28, pi = blockIdx.x % 28;
  int lt = 0;
  while ((lt+1)*(lt+2)/2 <= pi) lt++;
  int tt = pi - lt*(lt+1)/2;
  int tid = threadIdx.x;
  __shared__ __align__(16) float zl[32*PADK];
  __shared__ __align__(16) float vl[32*PADK];
  __shared__ __align__(16) float zt[32*PADK];
  __shared__ __align__(16) float vt[32*PADK];
  __shared__ float ps[8*32];
  const float* zb = z + b*12800;
  const float* vb = v + b*12800;
  int l0 = lt*32, t0 = tt*32;
  for (int k = tid; k < 2048; k += 256){
    int r = k >> 6, d = k & 63;
    int lr = l0 + r, tr = t0 + r;
    zl[r*PADK+d] = (lr < L_) ? zb[lr*64+d] : 0.f;
    vl[r*PADK+d] = (lr < L_) ? vb[lr*64+d] : 0.f;
    zt[r*PADK+d] = (tr < L_) ? zb[tr*64+d] : 0.f;
    vt[r*PADK+d] = (tr < L_) ? vb[tr*64+d] : 0.f;
  }
  __syncthreads();
  {
    int r = tid & 31, c4 = tid >> 5;   // 32 rows x 8 col-groups of 4
    int c0 = c4 * 4;
    float az[4] = {0,0,0,0}, av[4] = {0,0,0,0};
    for (int k = 0; k < 64; k += 4){
      float4 zr = *(const float4*)&zl[r*PADK+k];
      float4 vr = *(const float4*)&vl[r*PADK+k];
#pragma unroll
      for (int j = 0; j < 4; j++){
        float4 zc = *(const float4*)&zt[(c0+j)*PADK+k];
        az[j] += zr.x*zc.x + zr.y*zc.y + zr.z*zc.z + zr.w*zc.w;
        float4 vc = *(const float4*)&vt[(c0+j)*PADK+k];
        av[j] += vr.x*vc.x + vr.y*vc.y + vr.z*vc.z + vr.w*vc.w;
      }
    }
    int l = l0 + r;
    bool diag = (lt == tt);
    float part = 0.f;
#pragma unroll
    for (int j = 0; j < 4; j++){
      int c = c0 + j;
      float hv = az[j] * av[j];
      if (!diag || c <= r) part += hv;
      if (diag && c == r && l < L_) harr[b*L_ + l] = hv;
    }
    ps[c4*32 + r] = part;
  }
  __syncthreads();
  if (tid < 32){
    float s = 0.f;
#pragma unroll
    for (int c4i = 0; c4i < 8; c4i++) s += ps[c4i*32 + tid];
    int ll = l0 + tid;
    if (ll < L_) colpart[(b*L_ + ll)*8 + tt] = s;
  }
  if (lt == tt){
    // ---- carr: c_l = z_l^T PsL v_l (uses zl, vl) ----
    int w = tid >> 6, lane = tid & 63;
    float wacc[8] = {0,0,0,0,0,0,0,0};
    const float* psb = PsL + b*4096 + lane*64;
    for (int qq = 0; qq < 64; qq += 4){
      float4 p4 = *(const float4*)(psb + qq);
#pragma unroll
      for (int r8 = 0; r8 < 8; r8++){
        float4 v4 = *(const float4*)&vl[(w*8+r8)*PADK+qq];
        wacc[r8] += p4.x*v4.x + p4.y*v4.y + p4.z*v4.z + p4.w*v4.w;
      }
    }
#pragma unroll
    for (int r8 = 0; r8 < 8; r8++){
      int rr = w*8 + r8, l = l0 + rr;
      float c = wsum(zl[rr*PADK+lane] * wacc[r8]);
      if (lane == 0 && l < L_) carr[b*L_ + l] = c;
    }
    // ---- T1/T2: stage nq tile into zt (safe: main phase done) ----
    __syncthreads();
    for (int k = tid; k < 2048; k += 256){
      int r = k >> 6, d = k & 63, lr = l0 + r;
      zt[r*PADK+d] = (lr < L_) ? nq[(b*L_+lr)*64 + d] : 0.f;
    }
    __syncthreads();
    int r = tid & 31, c8 = tid >> 5, c0 = c8 * 8;
    float t1a[8] = {0,0,0,0,0,0,0,0}, t2a[8] = {0,0,0,0,0,0,0,0};
    const float* psm = PsL + b*4096;
    const float* pnm = pNAM + b*4096;
    for (int pp = 0; pp < 64; pp++){
      float nv = zt[r*PADK + pp];
      float4 a0 = *(const float4*)(psm + pp*64 + c0);
      float4 a1 = *(const float4*)(psm + pp*64 + c0 + 4);
      float4 b0 = *(const float4*)(pnm + pp*64 + c0);
      float4 b1 = *(const float4*)(pnm + pp*64 + c0 + 4);
      t1a[0] = fmaf(nv, a0.x, t1a[0]); t1a[1] = fmaf(nv, a0.y, t1a[1]);
      t1a[2] = fmaf(nv, a0.z, t1a[2]); t1a[3] = fmaf(nv, a0.w, t1a[3]);
      t1a[4] = fmaf(nv, a1.x, t1a[4]); t1a[5] = fmaf(nv, a1.y, t1a[5]);
      t1a[6] = fmaf(nv, a1.z, t1a[6]); t1a[7] = fmaf(nv, a1.w, t1a[7]);
      t2a[0] = fmaf(nv, b0.x, t2a[0]); t2a[1] = fmaf(nv, b0.y, t2a[1]);
      t2a[2] = fmaf(nv, b0.z, t2a[2]); t2a[3] = fmaf(nv, b0.w, t2a[3]);
      t2a[4] = fmaf(nv, b1.x, t2a[4]); t2a[5] = fmaf(nv, b1.y, t2a[5]);
      t2a[6] = fmaf(nv, b1.z, t2a[6]); t2a[7] = fmaf(nv, b1.w, t2a[7]);
    }
    int l = l0 + r;
    if (l < L_){
      float* t1p = T1 + (b*L_+l)*64 + c0;
      float* t2p = T2 + (b*L_+l)*64 + c0;
      *(float4*)(t1p)     = make_float4(t1a[0], t1a[1], t1a[2], t1a[3]);
      *(float4*)(t1p + 4) = make_float4(t1a[4], t1a[5], t1a[6], t1a[7]);
      *(float4*)(t2p)     = make_float4(t2a[0], t2a[1], t2a[2], t2a[3]);
      *(float4*)(t2p + 4) = make_float4(t2a[4], t2a[5], t2a[6], t2a[7]);
    }
  }
}

// K3b: per-b prefix sums: Zcum (per-lane independent) + 3 scalar scans (shfl-based)
__global__ __launch_bounds__(64) void k_cumsum(const float* __restrict__ z,
    const float* __restrict__ sz, const float* __restrict__ sv,
    const float* __restrict__ colpart, const float* __restrict__ harr, const float* __restrict__ carr,
    float* __restrict__ Zcum, float* __restrict__ cM, float* __restrict__ cR, float* __restrict__ cC){
  int b = blockIdx.x, lane = threadIdx.x;
  const float* zb = z + b*12800;
  float* Zb = Zcum + b*12800;
  float Zc = 0.f;
  for (int l = 0; l < 200; l += 4){
    float a0 = zb[(l+0)*64+lane];
    float a1 = zb[(l+1)*64+lane];
    float a2 = zb[(l+2)*64+lane];
    float a3 = zb[(l+3)*64+lane];
    Zc += a0; Zb[(l+0)*64+lane] = Zc;
    Zc += a1; Zb[(l+1)*64+lane] = Zc;
    Zc += a2; Zb[(l+2)*64+lane] = Zc;
    Zc += a3; Zb[(l+3)*64+lane] = Zc;
  }
  float carryM = 0.f, carryR = 0.f, carryC = 0.f;
#pragma unroll
  for (int c = 0; c < 4; c++){
    int l = c*64 + lane;
    bool valid = l < 200;
    int row = b*200 + l;
    float tcol = 0.f;
    if (valid){
      int ltile = l >> 5;
#pragma unroll
      for (int j = 0; j < 7; j++)
        if (j <= ltile) tcol += colpart[row*8 + j];
    }
    float tm = valid ? sz[row]*sv[row] : 0.f;
    float tr = valid ? 2.f*tcol - harr[row] : 0.f;
    float tc = valid ? carr[row] : 0.f;
#pragma unroll
    for (int o = 1; o < 64; o <<= 1){
      float y0 = __shfl_up(tm, o, 64);
      float y1 = __shfl_up(tr, o, 64);
      float y2 = __shfl_up(tc, o, 64);
      if (lane >= o){ tm += y0; tr += y1; tc += y2; }
    }
    tm += carryM; tr += carryR; tc += carryC;
    if (valid){ cM[row] = tm; cR[row] = tr; cC[row] = tc; }
    carryM = __shfl(tm, 63, 64);
    carryR = __shfl(tr, 63, 64);
    carryC = __shfl(tc, 63, 64);
  }
}

// K4: per (b,l), 256 thr: coeffs (wave0) + 4-wave-split causal attention + final LN + std partials
__global__ __launch_bounds__(256) void k_final(const float* __restrict__ nq, const float* __restrict__ z,
    const float* __restrict__ v, const float* __restrict__ q, const float* __restrict__ Zcum,
    const float* __restrict__ PzL, const float* __restrict__ mps2, const float* __restrict__ snq,
    const float* __restrict__ cM, const float* __restrict__ cR, const float* __restrict__ cC,
    const float* __restrict__ T1, const float* __restrict__ T2,
    float* __restrict__ out, float* __restrict__ Syr, float* __restrict__ Sy2r){
  int row = blockIdx.x;
  int b = row / 200, l = row % 200;
  int tid = threadIdx.x, lane = tid & 63, w = tid >> 6;
  __shared__ __align__(16) float nqs[64];
  __shared__ float sc[256];
  __shared__ float accs[256];
  if (tid < 64) nqs[tid] = nq[row*64 + tid];
  __syncthreads();
  float cAv = 0.f, cBv = 0.f, cCv = 0.f;
  if (w == 0){
    float zc = Zcum[row*64 + lane];
    float s1 = wsum(zc), s2 = wsum(zc*zc);
    float mz = s1*(1.f/64.f), vz = s2*(1.f/64.f) - mz*mz;
    float zf = (zc - mz) * rsqrtf(vz + 1e-5f) + PzL[b*64 + lane];
    float zl2 = wsum(zf*zf);
    float a = sqrtf(zl2) + 1e-8f;
    float m = cM[row] * (1.f/4096.f);
    float var = cR[row] * (1.f/4096.f) - m*m;
    float inv = rsqrtf(var + 1e-5f);
    float varT = inv*inv*var + 2.f*inv*cC[row]*(1.f/4096.f) + mps2[b];
    float invT = rsqrtf(varT + 1e-5f*a*a);
    cAv = invT*inv;
    cBv = invT*inv*m*snq[row];
    cCv = invT;
    float y = q[row*64 + lane] / fmaxf(zf, 1e-6f);
    float ys = wsum(y), ys2 = wsum(y*y);
    if (lane == 0){ Syr[row] = ys; Sy2r[row] = ys2; }
  }
  // attention: wave w owns chunk tbase = ((w+3)&3)*64  (wave0 -> 192, mostly idle)
  int tbase = ((w + 3) & 3) * 64;
  const float* zb = z + b*12800;
  const float* vb = v + b*12800;
  float acc = 0.f;
  if (tbase <= l){
    int t = tbase + lane;
    float s = 0.f;
    if (t <= l){
      const float* zr = zb + t*64;
#pragma unroll
      for (int dd = 0; dd < 64; dd += 4){
        float4 za = *(const float4*)(zr + dd);
        s += nqs[dd]*za.x + nqs[dd+1]*za.y + nqs[dd+2]*za.z + nqs[dd+3]*za.w;
      }
    }
    sc[tid] = s;
    int tmax = min(63, l - tbase);
    const float* vrb = vb + tbase*64 + lane;
    const float* scw = sc + w*64;
    float a0 = 0.f, a1 = 0.f, a2 = 0.f, a3 = 0.f;
    int tt = 0;
    for (; tt + 3 <= tmax; tt += 4){
      a0 = fmaf(scw[tt],   vrb[tt*64],       a0);
      a1 = fmaf(scw[tt+1], vrb[tt*64 + 64],  a1);
      a2 = fmaf(scw[tt+2], vrb[tt*64 + 128], a2);
      a3 = fmaf(scw[tt+3], vrb[tt*64 + 192], a3);
    }
    for (; tt <= tmax; tt++) a0 = fmaf(scw[tt], vrb[tt*64], a0);
    acc = (a0 + a1) + (a2 + a3);
  }
  accs[tid] = acc;
  __syncthreads();
  if (w == 0){
    float at = accs[lane] + accs[lane+64] + accs[lane+128] + accs[lane+192];
    float t1v = T1[row*64 + lane];
    float t2v = T2[row*64 + lane];
    float NA1 = cAv*at - cBv + cCv*t1v + t2v;
    float r1 = wsum(NA1), r2 = wsum(NA1*NA1);
    float mm = r1*(1.f/64.f), vv = r2*(1.f/64.f) - mm*mm;
    out[row*64 + lane] = (NA1 - mm) * rsqrtf(vv + 1e-5f);
  }
}

// K5: finalize std (ddof=1) over all B*L*D elements; reduce 6400 row partials
__global__ __launch_bounds__(256) void k_std(const float* __restrict__ Syr, const float* __restrict__ Sy2r,
    float* __restrict__ out){
  __shared__ float redA[4], redB[4];
  int tid = threadIdx.x, lane = tid & 63, g = tid >> 6;
  float a = 0.f, b2 = 0.f;
  for (int i = tid; i < 6400; i += 256){ a += Syr[i]; b2 += Sy2r[i]; }
  a = wsum(a); b2 = wsum(b2);
  if (lane == 0){ redA[g] = a; redB[g] = b2; }
  __syncthreads();
  if (tid == 0){
    float A = redA[0]+redA[1]+redA[2]+redA[3];
    float B2 = redB[0]+redB[1]+redB[2]+redB[3];
    const float N = 409600.f;
    float var = (B2 - A*A/N) / (N - 1.f);
    out[409600] = sqrtf(fmaxf(var, 0.f));
  }
}

extern "C" void kernel_launch(void* const* d_in, const int* in_sizes, int n_in,
                              void* d_out, int out_size, void* d_ws, size_t ws_size,
                              hipStream_t stream) {
  const int*   uid    = (const int*)d_in[0];
  const float* seqs   = (const float*)d_in[1];
  const float* P      = (const float*)d_in[2];
  const float* S      = (const float*)d_in[3];
  const float* prev_z = (const float*)d_in[4];
  const float* prev_s = (const float*)d_in[5];
  const float* Wq     = (const float*)d_in[6];
  const float* bq     = (const float*)d_in[7];
  const float* Wk     = (const float*)d_in[8];
  const float* bk     = (const float*)d_in[9];
  const float* Wv     = (const float*)d_in[10];
  const float* bv     = (const float*)d_in[11];
  float* w   = (float*)d_ws;
  float* out = (float*)d_out;

  k_transpose<<<192, 256, 0, stream>>>(Wq, Wk, Wv, w + OFF_WT);
  k_qzv<<<400, 256, 0, stream>>>(seqs, w + OFF_WT, bq, bk, bv,
      w + OFF_Q, w + OFF_NQ, w + OFF_Z, w + OFF_V, w + OFF_SZ, w + OFF_SV, w + OFF_SNQ);
  k_prompt<<<64, 256, 0, stream>>>(P, S, uid, prev_z, prev_s, w + OFF_WT, bk, bv,
      w + OFF_PZL, w + OFF_PSL, w + OFF_MPS2, w + OFF_PNAM);
  k_gram_tile<<<B_*28, 256, 0, stream>>>(w + OFF_Z, w + OFF_V, w + OFF_NQ,
      w + OFF_PSL, w + OFF_PNAM,
      w + OFF_CP, w + OFF_H, w + OFF_C, w + OFF_T1, w + OFF_T2);
  k_cumsum<<<32, 64, 0, stream>>>(w + OFF_Z, w + OFF_SZ, w + OFF_SV,
      w + OFF_CP, w + OFF_H, w + OFF_C,
      w + OFF_ZC, w + OFF_CM, w + OFF_CR, w + OFF_CCP);
  k_final<<<6400, 256, 0, stream>>>(w + OFF_NQ, w + OFF_Z, w + OFF_V, w + OFF_Q, w + OFF_ZC,
      w + OFF_PZL, w + OFF_MPS2, w + OFF_SNQ,
      w + OFF_CM, w + OFF_CR, w + OFF_CCP,
      w + OFF_T1, w + OFF_T2,
      out, w + OFF_SYR, w + OFF_SY2R);
  k_std<<<1, 256, 0, stream>>>(w + OFF_SYR, w + OFF_SY2R, out);
}

// Round 5
// 156.909 us; speedup vs baseline: 1.2809x; 1.2809x over previous
//
#include <hip/hip_runtime.h>
#include <math.h>

// Problem constants
#define B_   32
#define L_   200
#define DIN_ 256
#define D_   64
#define PL_  8

// ws layout (float offsets)
#define OFF_WT    0         // 3*16384 transposed weights [i][d]
#define OFF_Q     49152     // B*L*D
#define OFF_NQ    458752
#define OFF_Z     868352
#define OFF_V     1277952
#define OFF_SZ    1687552   // B*L
#define OFF_SV    1693952
#define OFF_SNQ   1700352
#define OFF_PZL   1706752   // B*D
#define OFF_PSL   1708800   // B*D*D
#define OFF_PNAM  1839872   // B*D*D
#define OFF_MPS2  1970944   // B
#define OFF_H     1977376   // B*L diag terms
#define OFF_C     1983776   // B*L carr
#define OFF_CM    1990176   // B*L prefix of sz*sv
#define OFF_CR    1996576   // B*L prefix of 2*col-h
#define OFF_CCP   2002976   // B*L prefix of carr
#define OFF_SYR   2009376   // B*L row partials for std
#define OFF_SY2R  2015776   // B*L
#define OFF_ZC    2022176   // B*L*D cumsum of z
#define OFF_CP    2431776   // B*L*8 colsum partials per t-tile
#define OFF_T1    2482976   // B*L*D  NQ.PsL
#define OFF_T2    2892576   // B*L*D  NQ.pNAM
#define OFF_NAP   3302176   // B*7*8*32*64 attention partials
// end: 6972192 floats ~ 27.9 MB

__device__ __forceinline__ float wsum(float x){
#pragma unroll
  for (int o = 32; o > 0; o >>= 1) x += __shfl_xor(x, o, 64);
  return x;
}
__device__ __forceinline__ float eluf(float x){ return x > 0.f ? x : expm1f(x); }

// K0: transpose Wq,Wk,Wv [64,256] -> [256,64]
__global__ __launch_bounds__(256) void k_transpose(const float* __restrict__ Wq,
    const float* __restrict__ Wk, const float* __restrict__ Wv, float* __restrict__ wt){
  int idx = blockIdx.x*256 + threadIdx.x;
  if (idx >= 3*16384) return;
  int m = idx >> 14, r = idx & 16383, i = r >> 6, d = r & 63;
  const float* W = (m==0) ? Wq : ((m==1) ? Wk : Wv);
  wt[m*16384 + i*64 + d] = W[d*256 + i];
}

// K1: q,z,v GEMMs + per-row stats. 16 rows/block, 256 thr (wave g owns rows g+4j)
__global__ __launch_bounds__(256) void k_qzv(const float* __restrict__ x, const float* __restrict__ Wt,
    const float* __restrict__ bq, const float* __restrict__ bk, const float* __restrict__ bv,
    float* __restrict__ q, float* __restrict__ nq, float* __restrict__ z, float* __restrict__ v,
    float* __restrict__ sz, float* __restrict__ sv, float* __restrict__ snq){
  __shared__ float xs[16*256];
  int row0 = blockIdx.x * 16;
  int tid = threadIdx.x, d = tid & 63, g = tid >> 6;
  for (int k = tid; k < 4096; k += 256) xs[k] = x[row0*256 + k];
  __syncthreads();
  const float* Wtq = Wt;
  const float* Wtk = Wt + 16384;
  const float* Wtv = Wt + 32768;
  float aq[4] = {0,0,0,0}, ak[4] = {0,0,0,0}, av[4] = {0,0,0,0};
  for (int i = 0; i < 256; i++){
    float wq = Wtq[i*64+d], wk = Wtk[i*64+d], wv = Wtv[i*64+d];
#pragma unroll
    for (int j = 0; j < 4; j++){
      float xv = xs[(g+4*j)*256 + i];
      aq[j] = fmaf(xv, wq, aq[j]);
      ak[j] = fmaf(xv, wk, ak[j]);
      av[j] = fmaf(xv, wv, av[j]);
    }
  }
  float bqd = bq[d], bkd = bk[d], bvd = bv[d];
#pragma unroll
  for (int j = 0; j < 4; j++){
    int r = row0 + g + 4*j;
    float qv = eluf(aq[j] + bqd);
    float zv = eluf(ak[j] + bkd);
    float vv = av[j] + bvd;
    float sq2 = wsum(qv*qv);
    float sq1 = wsum(qv);
    float szv = wsum(zv);
    float svv = wsum(vv);
    float inv = 1.f / (sqrtf(sq2) + 1e-8f);
    q[r*64+d] = qv; nq[r*64+d] = qv*inv; z[r*64+d] = zv; v[r*64+d] = vv;
    if (d == 0){ sz[r] = szv; sv[r] = svv; snq[r] = sq1*inv; }
  }
}

// K2: prompt paths, split: block g: b = g&31, path = g>>5 (0: P -> PzL,PsL,mps2; 1: S -> pNAM)
__global__ __launch_bounds__(256) void k_prompt(const float* __restrict__ P, const float* __restrict__ Sp,
    const int* __restrict__ uid, const float* __restrict__ prev_z, const float* __restrict__ prev_s,
    const float* __restrict__ Wt, const float* __restrict__ bk, const float* __restrict__ bv,
    float* __restrict__ PzL, float* __restrict__ PsL, float* __restrict__ mps2, float* __restrict__ pNAM){
  int g = blockIdx.x, b = g & 31, path = g >> 5;
  int tid = threadIdx.x;
  __shared__ float xs[2048];
  __shared__ float zs[512], vs[512];
  __shared__ float red[4];
  __shared__ float facs;
  const float* src = path ? Sp : P;
  for (int k = tid; k < 2048; k += 256) xs[k] = src[b*2048 + k];
  __syncthreads();
  const float* Wtk = Wt + 16384;
  const float* Wtv = Wt + 32768;
  for (int idx = tid; idx < 512; idx += 256){
    int t = idx >> 6, d = idx & 63;
    float ak = 0.f, av = 0.f;
    for (int i = 0; i < 256; i++){
      float xv = xs[t*256+i];
      ak = fmaf(xv, Wtk[i*64+d], ak);
      av = fmaf(xv, Wtv[i*64+d], av);
    }
    zs[idx] = eluf(ak + bk[d]); vs[idx] = av + bv[d];
  }
  __syncthreads();
  float spv[16];
  float l1 = 0.f, l2 = 0.f;
  int p = tid >> 2, q0 = (tid & 3) * 16;
#pragma unroll
  for (int k = 0; k < 16; k++){
    int qq = q0 + k;
    float sp = 0.f;
#pragma unroll
    for (int t = 0; t < 8; t++) sp = fmaf(zs[t*64+p], vs[t*64+qq], sp);
    spv[k] = sp; l1 += sp; l2 += sp*sp;
  }
  float tot0, tot1;
  {
    float val = wsum(l1);
    if ((tid & 63) == 0) red[tid >> 6] = val;
    __syncthreads();
    tot0 = red[0] + red[1] + red[2] + red[3];
    __syncthreads();
    val = wsum(l2);
    if ((tid & 63) == 0) red[tid >> 6] = val;
    __syncthreads();
    tot1 = red[0] + red[1] + red[2] + red[3];
  }
  float mP = tot0 * (1.f/4096.f);
  float varP = tot1 * (1.f/4096.f) - mP*mP;
  float invv = rsqrtf(varP + 1e-5f);
  if (path == 0){
    if (tid == 0) mps2[b] = varP * invv * invv;  // E[PsL^2]
    if (tid < 64){
      int d = tid;
      float zc = 0.f;
#pragma unroll
      for (int t = 0; t < 8; t++) zc += zs[t*64+d];
      float s1 = wsum(zc), s2 = wsum(zc*zc);
      float mz = s1*(1.f/64.f), vz = s2*(1.f/64.f) - mz*mz;
      PzL[b*64+d] = (zc - mz) * rsqrtf(vz + 1e-5f);
    }
#pragma unroll
    for (int k = 0; k < 16; k++){
      int o = p*64 + q0 + k;
      PsL[b*4096 + o] = (spv[k] - mP) * invv;
    }
  } else {
    int u = uid[b];
    if (tid < 64){
      int d = tid;
      float zc = 0.f;
#pragma unroll
      for (int t = 0; t < 8; t++) zc += zs[t*64+d];
      float s1 = wsum(zc), s2 = wsum(zc*zc);
      float mz = s1*(1.f/64.f), vz = s2*(1.f/64.f) - mz*mz;
      float szl = (zc - mz) * rsqrtf(vz + 1e-5f);
      float pzv = prev_z[u*64 + d];
      float zu = pzv + szl;
      float zl2 = wsum(zu*zu);
      float psumv = wsum(pzv);
      float fac = ((psumv != 0.f) ? 1.f : 0.f) / (sqrtf(zl2) + 1e-8f);
      if (d == 0) facs = fac;
    }
    __syncthreads();
    float fac = facs;
    const float* psrow = prev_s + (size_t)u * 4096;
#pragma unroll
    for (int k = 0; k < 16; k++){
      int o = p*64 + q0 + k;
      pNAM[b*4096 + o] = (psrow[o] + (spv[k] - mP) * invv) * fac;
    }
  }
}

// K3a: fused tiled Gram + Score + AV partials. Grid = B*35.
//  pi<28: tile-pair (lt,tt<=lt): colsum partials, diag h, score=nq_l.z_t, NAP partial = score.V,
//         diag also carr = z^T PsL v.
//  pi in [28,35): T1 = NQ.PsL, T2 = NQ.pNAM for row-tile (pi-28).
#define PADK 68
__global__ __launch_bounds__(256) void k_gram_tile(const float* __restrict__ z, const float* __restrict__ v,
    const float* __restrict__ nq, const float* __restrict__ PsL, const float* __restrict__ pNAM,
    float* __restrict__ colpart, float* __restrict__ harr, float* __restrict__ carr,
    float* __restrict__ NAP, float* __restrict__ T1, float* __restrict__ T2){
  int b = blockIdx.x / 35, pi = blockIdx.x % 35;
  int tid = threadIdx.x;
  __shared__ __align__(16) float smem[12192];
  float* zl  = smem;           // 32*PADK
  float* vl  = smem + 2176;
  float* zt  = smem + 4352;
  float* vt  = smem + 6528;
  float* nqt = smem + 8704;    // 32*PADK (or stride-65 in T-branch)
  float* scs = smem + 10880;   // 32*33
  float* ps  = smem + 11936;   // 8*32

  if (pi >= 28){
    // ---- T1/T2 for row-tile rt ----
    int rt = pi - 28, l0 = rt*32;
    for (int k = tid; k < 2048; k += 256){
      int r = k >> 6, d = k & 63, lr = l0 + r;
      nqt[r*65+d] = (lr < L_) ? nq[(b*L_+lr)*64 + d] : 0.f;
    }
    __syncthreads();
    int r = tid & 31, c8 = tid >> 5, c0 = c8 * 8;
    float t1a[8] = {0,0,0,0,0,0,0,0}, t2a[8] = {0,0,0,0,0,0,0,0};
    const float* psm = PsL + b*4096;
    const float* pnm = pNAM + b*4096;
    for (int pp = 0; pp < 64; pp++){
      float nv = nqt[r*65 + pp];
      float4 a0 = *(const float4*)(psm + pp*64 + c0);
      float4 a1 = *(const float4*)(psm + pp*64 + c0 + 4);
      float4 b0 = *(const float4*)(pnm + pp*64 + c0);
      float4 b1 = *(const float4*)(pnm + pp*64 + c0 + 4);
      t1a[0] = fmaf(nv, a0.x, t1a[0]); t1a[1] = fmaf(nv, a0.y, t1a[1]);
      t1a[2] = fmaf(nv, a0.z, t1a[2]); t1a[3] = fmaf(nv, a0.w, t1a[3]);
      t1a[4] = fmaf(nv, a1.x, t1a[4]); t1a[5] = fmaf(nv, a1.y, t1a[5]);
      t1a[6] = fmaf(nv, a1.z, t1a[6]); t1a[7] = fmaf(nv, a1.w, t1a[7]);
      t2a[0] = fmaf(nv, b0.x, t2a[0]); t2a[1] = fmaf(nv, b0.y, t2a[1]);
      t2a[2] = fmaf(nv, b0.z, t2a[2]); t2a[3] = fmaf(nv, b0.w, t2a[3]);
      t2a[4] = fmaf(nv, b1.x, t2a[4]); t2a[5] = fmaf(nv, b1.y, t2a[5]);
      t2a[6] = fmaf(nv, b1.z, t2a[6]); t2a[7] = fmaf(nv, b1.w, t2a[7]);
    }
    int l = l0 + r;
    if (l < L_){
      float* t1p = T1 + (b*L_+l)*64 + c0;
      float* t2p = T2 + (b*L_+l)*64 + c0;
      *(float4*)(t1p)     = make_float4(t1a[0], t1a[1], t1a[2], t1a[3]);
      *(float4*)(t1p + 4) = make_float4(t1a[4], t1a[5], t1a[6], t1a[7]);
      *(float4*)(t2p)     = make_float4(t2a[0], t2a[1], t2a[2], t2a[3]);
      *(float4*)(t2p + 4) = make_float4(t2a[4], t2a[5], t2a[6], t2a[7]);
    }
    return;
  }
  // ---- Gram/Score/AV tile-pair ----
  int lt = 0;
  while ((lt+1)*(lt+2)/2 <= pi) lt++;
  int tt = pi - lt*(lt+1)/2;
  int l0 = lt*32, t0 = tt*32;
  bool diag = (lt == tt);
  const float* zb = z + b*12800;
  const float* vb = v + b*12800;
  const float* nqb = nq + b*12800;
  for (int k = tid; k < 2048; k += 256){
    int r = k >> 6, d = k & 63;
    int lr = l0 + r, tr = t0 + r;
    bool lv = lr < L_, tv = tr < L_;
    zl[r*PADK+d]  = lv ? zb[lr*64+d] : 0.f;
    vl[r*PADK+d]  = lv ? vb[lr*64+d] : 0.f;
    nqt[r*PADK+d] = lv ? nqb[lr*64+d] : 0.f;
    zt[r*PADK+d]  = tv ? zb[tr*64+d] : 0.f;
    vt[r*PADK+d]  = tv ? vb[tr*64+d] : 0.f;
  }
  __syncthreads();
  {
    int r = tid & 31, c4 = tid >> 5, c0 = c4 * 4;  // 32 rows x 8 col-groups of 4
    float az[4] = {0,0,0,0}, av[4] = {0,0,0,0}, an[4] = {0,0,0,0};
    for (int k = 0; k < 64; k += 4){
      float4 zr = *(const float4*)&zl[r*PADK+k];
      float4 vr = *(const float4*)&vl[r*PADK+k];
      float4 nr = *(const float4*)&nqt[r*PADK+k];
#pragma unroll
      for (int j = 0; j < 4; j++){
        float4 zc = *(const float4*)&zt[(c0+j)*PADK+k];
        az[j] += zr.x*zc.x + zr.y*zc.y + zr.z*zc.z + zr.w*zc.w;
        an[j] += nr.x*zc.x + nr.y*zc.y + nr.z*zc.z + nr.w*zc.w;
        float4 vc = *(const float4*)&vt[(c0+j)*PADK+k];
        av[j] += vr.x*vc.x + vr.y*vc.y + vr.z*vc.z + vr.w*vc.w;
      }
    }
    int l = l0 + r;
    float part = 0.f;
#pragma unroll
    for (int j = 0; j < 4; j++){
      int c = c0 + j;
      bool keep = (!diag || c <= r);
      float hv = az[j] * av[j];
      if (keep) part += hv;
      if (diag && c == r && l < L_) harr[b*L_ + l] = hv;
      scs[r*33 + c] = keep ? an[j] : 0.f;
    }
    ps[c4*32 + r] = part;
  }
  __syncthreads();
  if (tid < 32){
    float s = 0.f;
#pragma unroll
    for (int c4i = 0; c4i < 8; c4i++) s += ps[c4i*32 + tid];
    int ll = l0 + tid;
    if (ll < L_) colpart[(b*L_ + ll)*8 + tt] = s;
  }
  // AV: NAP[r][d] = sum_c scs[r][c] * vt[c][d]
  {
    int r = tid & 31, d2 = tid >> 5, d0 = d2 * 8;
    float acc8[8] = {0,0,0,0,0,0,0,0};
    for (int c = 0; c < 32; c++){
      float s = scs[r*33 + c];
      float4 v0 = *(const float4*)&vt[c*PADK + d0];
      float4 v1 = *(const float4*)&vt[c*PADK + d0 + 4];
      acc8[0] = fmaf(s, v0.x, acc8[0]); acc8[1] = fmaf(s, v0.y, acc8[1]);
      acc8[2] = fmaf(s, v0.z, acc8[2]); acc8[3] = fmaf(s, v0.w, acc8[3]);
      acc8[4] = fmaf(s, v1.x, acc8[4]); acc8[5] = fmaf(s, v1.y, acc8[5]);
      acc8[6] = fmaf(s, v1.z, acc8[6]); acc8[7] = fmaf(s, v1.w, acc8[7]);
    }
    float* nap = NAP + ((size_t)((b*7 + lt)*8 + tt))*2048 + r*64 + d0;
    *(float4*)(nap)     = make_float4(acc8[0], acc8[1], acc8[2], acc8[3]);
    *(float4*)(nap + 4) = make_float4(acc8[4], acc8[5], acc8[6], acc8[7]);
  }
  if (diag){
    // carr: c_l = z_l^T PsL v_l
    int w = tid >> 6, lane = tid & 63;
    float wacc[8] = {0,0,0,0,0,0,0,0};
    const float* psb = PsL + b*4096 + lane*64;
    for (int qq = 0; qq < 64; qq += 4){
      float4 p4 = *(const float4*)(psb + qq);
#pragma unroll
      for (int r8 = 0; r8 < 8; r8++){
        float4 v4 = *(const float4*)&vl[(w*8+r8)*PADK+qq];
        wacc[r8] += p4.x*v4.x + p4.y*v4.y + p4.z*v4.z + p4.w*v4.w;
      }
    }
#pragma unroll
    for (int r8 = 0; r8 < 8; r8++){
      int rr = w*8 + r8, l = l0 + rr;
      float c = wsum(zl[rr*PADK+lane] * wacc[r8]);
      if (lane == 0 && l < L_) carr[b*L_ + l] = c;
    }
  }
}

// K3b: per-b prefix sums: Zcum + 3 scalar scans (shfl-based)
__global__ __launch_bounds__(64) void k_cumsum(const float* __restrict__ z,
    const float* __restrict__ sz, const float* __restrict__ sv,
    const float* __restrict__ colpart, const float* __restrict__ harr, const float* __restrict__ carr,
    float* __restrict__ Zcum, float* __restrict__ cM, float* __restrict__ cR, float* __restrict__ cC){
  int b = blockIdx.x, lane = threadIdx.x;
  const float* zb = z + b*12800;
  float* Zb = Zcum + b*12800;
  float Zc = 0.f;
  for (int l = 0; l < 200; l += 4){
    float a0 = zb[(l+0)*64+lane];
    float a1 = zb[(l+1)*64+lane];
    float a2 = zb[(l+2)*64+lane];
    float a3 = zb[(l+3)*64+lane];
    Zc += a0; Zb[(l+0)*64+lane] = Zc;
    Zc += a1; Zb[(l+1)*64+lane] = Zc;
    Zc += a2; Zb[(l+2)*64+lane] = Zc;
    Zc += a3; Zb[(l+3)*64+lane] = Zc;
  }
  float carryM = 0.f, carryR = 0.f, carryC = 0.f;
#pragma unroll
  for (int c = 0; c < 4; c++){
    int l = c*64 + lane;
    bool valid = l < 200;
    int row = b*200 + l;
    float tcol = 0.f;
    if (valid){
      int ltile = l >> 5;
#pragma unroll
      for (int j = 0; j < 7; j++)
        if (j <= ltile) tcol += colpart[row*8 + j];
    }
    float tm = valid ? sz[row]*sv[row] : 0.f;
    float tr = valid ? 2.f*tcol - harr[row] : 0.f;
    float tc = valid ? carr[row] : 0.f;
#pragma unroll
    for (int o = 1; o < 64; o <<= 1){
      float y0 = __shfl_up(tm, o, 64);
      float y1 = __shfl_up(tr, o, 64);
      float y2 = __shfl_up(tc, o, 64);
      if (lane >= o){ tm += y0; tr += y1; tc += y2; }
    }
    tm += carryM; tr += carryR; tc += carryC;
    if (valid){ cM[row] = tm; cR[row] = tr; cC[row] = tc; }
    carryM = __shfl(tm, 63, 64);
    carryR = __shfl(tr, 63, 64);
    carryC = __shfl(tc, 63, 64);
  }
}

// K4: per (b,l), 64 thr: reduce NAP partials + coefficients + final LN + std partials
__global__ __launch_bounds__(64) void k_finred(const float* __restrict__ q, const float* __restrict__ Zcum,
    const float* __restrict__ PzL, const float* __restrict__ mps2, const float* __restrict__ snq,
    const float* __restrict__ cM, const float* __restrict__ cR, const float* __restrict__ cC,
    const float* __restrict__ T1, const float* __restrict__ T2, const float* __restrict__ NAP,
    float* __restrict__ out, float* __restrict__ Syr, float* __restrict__ Sy2r){
  int row = blockIdx.x;
  int b = row / 200, l = row % 200;
  int lane = threadIdx.x;
  int lt = l >> 5, r = l & 31;
  const float* np_ = NAP + ((size_t)(b*7 + lt))*8*2048 + r*64 + lane;
  float acc = 0.f;
  for (int tt = 0; tt <= lt; tt++) acc += np_[tt*2048];
  float zc = Zcum[row*64 + lane];
  float s1 = wsum(zc), s2 = wsum(zc*zc);
  float mz = s1*(1.f/64.f), vz = s2*(1.f/64.f) - mz*mz;
  float zf = (zc - mz) * rsqrtf(vz + 1e-5f) + PzL[b*64 + lane];
  float zl2 = wsum(zf*zf);
  float a = sqrtf(zl2) + 1e-8f;
  float m = cM[row] * (1.f/4096.f);
  float var = cR[row] * (1.f/4096.f) - m*m;
  float inv = rsqrtf(var + 1e-5f);
  float varT = inv*inv*var + 2.f*inv*cC[row]*(1.f/4096.f) + mps2[b];
  float invT = rsqrtf(varT + 1e-5f*a*a);
  float cAv = invT*inv;
  float cBv = invT*inv*m*snq[row];
  float cCv = invT;
  float y = q[row*64 + lane] / fmaxf(zf, 1e-6f);
  float ys = wsum(y), ys2 = wsum(y*y);
  if (lane == 0){ Syr[row] = ys; Sy2r[row] = ys2; }
  float NA1 = cAv*acc - cBv + cCv*T1[row*64 + lane] + T2[row*64 + lane];
  float r1 = wsum(NA1), r2 = wsum(NA1*NA1);
  float mm = r1*(1.f/64.f), vv = r2*(1.f/64.f) - mm*mm;
  out[row*64 + lane] = (NA1 - mm) * rsqrtf(vv + 1e-5f);
}

// K5: finalize std (ddof=1); reduce 6400 row partials
__global__ __launch_bounds__(256) void k_std(const float* __restrict__ Syr, const float* __restrict__ Sy2r,
    float* __restrict__ out){
  __shared__ float redA[4], redB[4];
  int tid = threadIdx.x, lane = tid & 63, g = tid >> 6;
  float a = 0.f, b2 = 0.f;
  for (int i = tid; i < 6400; i += 256){ a += Syr[i]; b2 += Sy2r[i]; }
  a = wsum(a); b2 = wsum(b2);
  if (lane == 0){ redA[g] = a; redB[g] = b2; }
  __syncthreads();
  if (tid == 0){
    float A = redA[0]+redA[1]+redA[2]+redA[3];
    float B2 = redB[0]+redB[1]+redB[2]+redB[3];
    const float N = 409600.f;
    float var = (B2 - A*A/N) / (N - 1.f);
    out[409600] = sqrtf(fmaxf(var, 0.f));
  }
}

extern "C" void kernel_launch(void* const* d_in, const int* in_sizes, int n_in,
                              void* d_out, int out_size, void* d_ws, size_t ws_size,
                              hipStream_t stream) {
  const int*   uid    = (const int*)d_in[0];
  const float* seqs   = (const float*)d_in[1];
  const float* P      = (const float*)d_in[2];
  const float* S      = (const float*)d_in[3];
  const float* prev_z = (const float*)d_in[4];
  const float* prev_s = (const float*)d_in[5];
  const float* Wq     = (const float*)d_in[6];
  const float* bq     = (const float*)d_in[7];
  const float* Wk     = (const float*)d_in[8];
  const float* bk     = (const float*)d_in[9];
  const float* Wv     = (const float*)d_in[10];
  const float* bv     = (const float*)d_in[11];
  float* w   = (float*)d_ws;
  float* out = (float*)d_out;

  k_transpose<<<192, 256, 0, stream>>>(Wq, Wk, Wv, w + OFF_WT);
  k_qzv<<<400, 256, 0, stream>>>(seqs, w + OFF_WT, bq, bk, bv,
      w + OFF_Q, w + OFF_NQ, w + OFF_Z, w + OFF_V, w + OFF_SZ, w + OFF_SV, w + OFF_SNQ);
  k_prompt<<<64, 256, 0, stream>>>(P, S, uid, prev_z, prev_s, w + OFF_WT, bk, bv,
      w + OFF_PZL, w + OFF_PSL, w + OFF_MPS2, w + OFF_PNAM);
  k_gram_tile<<<B_*35, 256, 0, stream>>>(w + OFF_Z, w + OFF_V, w + OFF_NQ,
      w + OFF_PSL, w + OFF_PNAM,
      w + OFF_CP, w + OFF_H, w + OFF_C, w + OFF_NAP, w + OFF_T1, w + OFF_T2);
  k_cumsum<<<32, 64, 0, stream>>>(w + OFF_Z, w + OFF_SZ, w + OFF_SV,
      w + OFF_CP, w + OFF_H, w + OFF_C,
      w + OFF_ZC, w + OFF_CM, w + OFF_CR, w + OFF_CCP);
  k_finred<<<6400, 64, 0, stream>>>(w + OFF_Q, w + OFF_ZC,
      w + OFF_PZL, w + OFF_MPS2, w + OFF_SNQ,
      w + OFF_CM, w + OFF_CR, w + OFF_CCP,
      w + OFF_T1, w + OFF_T2, w + OFF_NAP,
      out, w + OFF_SYR, w + OFF_SY2R);
  k_std<<<1, 256, 0, stream>>>(w + OFF_SYR, w + OFF_SY2R, out);
}

// Round 6
// 139.307 us; speedup vs baseline: 1.4427x; 1.1264x over previous
//
#include <hip/hip_runtime.h>
#include <math.h>

// Problem constants
#define B_   32
#define L_   200
#define DIN_ 256
#define D_   64
#define PL_  8

// ws layout (float offsets)
#define OFF_WT    0         // 3*16384 transposed weights [i][d]
#define OFF_Q     49152     // B*L*D
#define OFF_NQ    458752
#define OFF_Z     868352
#define OFF_V     1277952
#define OFF_SZ    1687552   // B*L
#define OFF_SV    1693952
#define OFF_SNQ   1700352
#define OFF_PZL   1706752   // B*D
#define OFF_PSL   1708800   // B*D*D
#define OFF_PNAM  1839872   // B*D*D
#define OFF_MPS2  1970944   // B
#define OFF_H     1970976   // B*L diag terms
#define OFF_C     1977376   // B*L carr
#define OFF_CM    1983776   // B*L prefix of sz*sv
#define OFF_CR    1990176   // B*L prefix of 2*col-h
#define OFF_CCP   1996576   // B*L prefix of carr
#define OFF_SYR   2002976   // B*L row partials for std
#define OFF_SY2R  2009376   // B*L
#define OFF_ZC    2015776   // B*L*D cumsum of z
#define OFF_CP    2425376   // B*L*4 colsum partials per 64-col tile
#define OFF_T1    2450976   // B*L*D  NQ.PsL
#define OFF_T2    2860576   // B*L*D  NQ.pNAM
#define OFF_NAP   3270176   // B*4*4*64*64 attention partials
// end: 5367328 floats ~ 21.5 MB

__device__ __forceinline__ float wsum(float x){
#pragma unroll
  for (int o = 32; o > 0; o >>= 1) x += __shfl_xor(x, o, 64);
  return x;
}
__device__ __forceinline__ float eluf(float x){ return x > 0.f ? x : expm1f(x); }

// K0: transpose Wq,Wk,Wv [64,256] -> [256,64]
__global__ __launch_bounds__(256) void k_transpose(const float* __restrict__ Wq,
    const float* __restrict__ Wk, const float* __restrict__ Wv, float* __restrict__ wt){
  int idx = blockIdx.x*256 + threadIdx.x;
  if (idx >= 3*16384) return;
  int m = idx >> 14, r = idx & 16383, i = r >> 6, d = r & 63;
  const float* W = (m==0) ? Wq : ((m==1) ? Wk : Wv);
  wt[m*16384 + i*64 + d] = W[d*256 + i];
}

// K1: q,z,v GEMMs + per-row stats. 16 rows/block, 256 thr
__global__ __launch_bounds__(256) void k_qzv(const float* __restrict__ x, const float* __restrict__ Wt,
    const float* __restrict__ bq, const float* __restrict__ bk, const float* __restrict__ bv,
    float* __restrict__ q, float* __restrict__ nq, float* __restrict__ z, float* __restrict__ v,
    float* __restrict__ sz, float* __restrict__ sv, float* __restrict__ snq){
  __shared__ float xs[16*256];
  int row0 = blockIdx.x * 16;
  int tid = threadIdx.x, d = tid & 63, g = tid >> 6;
  for (int k = tid; k < 4096; k += 256) xs[k] = x[row0*256 + k];
  __syncthreads();
  const float* Wtq = Wt;
  const float* Wtk = Wt + 16384;
  const float* Wtv = Wt + 32768;
  float aq[4] = {0,0,0,0}, ak[4] = {0,0,0,0}, av[4] = {0,0,0,0};
  for (int i = 0; i < 256; i++){
    float wq = Wtq[i*64+d], wk = Wtk[i*64+d], wv = Wtv[i*64+d];
#pragma unroll
    for (int j = 0; j < 4; j++){
      float xv = xs[(g+4*j)*256 + i];
      aq[j] = fmaf(xv, wq, aq[j]);
      ak[j] = fmaf(xv, wk, ak[j]);
      av[j] = fmaf(xv, wv, av[j]);
    }
  }
  float bqd = bq[d], bkd = bk[d], bvd = bv[d];
#pragma unroll
  for (int j = 0; j < 4; j++){
    int r = row0 + g + 4*j;
    float qv = eluf(aq[j] + bqd);
    float zv = eluf(ak[j] + bkd);
    float vv = av[j] + bvd;
    float sq2 = wsum(qv*qv);
    float sq1 = wsum(qv);
    float szv = wsum(zv);
    float svv = wsum(vv);
    float inv = 1.f / (sqrtf(sq2) + 1e-8f);
    q[r*64+d] = qv; nq[r*64+d] = qv*inv; z[r*64+d] = zv; v[r*64+d] = vv;
    if (d == 0){ sz[r] = szv; sv[r] = svv; snq[r] = sq1*inv; }
  }
}

// K2: prompt paths, split: block g: b = g&31, path = g>>5 (0: P -> PzL,PsL,mps2; 1: S -> pNAM)
__global__ __launch_bounds__(256) void k_prompt(const float* __restrict__ P, const float* __restrict__ Sp,
    const int* __restrict__ uid, const float* __restrict__ prev_z, const float* __restrict__ prev_s,
    const float* __restrict__ Wt, const float* __restrict__ bk, const float* __restrict__ bv,
    float* __restrict__ PzL, float* __restrict__ PsL, float* __restrict__ mps2, float* __restrict__ pNAM){
  int g = blockIdx.x, b = g & 31, path = g >> 5;
  int tid = threadIdx.x;
  __shared__ float xs[2048];
  __shared__ float zs[512], vs[512];
  __shared__ float red[4];
  __shared__ float facs;
  const float* src = path ? Sp : P;
  for (int k = tid; k < 2048; k += 256) xs[k] = src[b*2048 + k];
  __syncthreads();
  const float* Wtk = Wt + 16384;
  const float* Wtv = Wt + 32768;
  for (int idx = tid; idx < 512; idx += 256){
    int t = idx >> 6, d = idx & 63;
    float ak = 0.f, av = 0.f;
    for (int i = 0; i < 256; i++){
      float xv = xs[t*256+i];
      ak = fmaf(xv, Wtk[i*64+d], ak);
      av = fmaf(xv, Wtv[i*64+d], av);
    }
    zs[idx] = eluf(ak + bk[d]); vs[idx] = av + bv[d];
  }
  __syncthreads();
  float spv[16];
  float l1 = 0.f, l2 = 0.f;
  int p = tid >> 2, q0 = (tid & 3) * 16;
#pragma unroll
  for (int k = 0; k < 16; k++){
    int qq = q0 + k;
    float sp = 0.f;
#pragma unroll
    for (int t = 0; t < 8; t++) sp = fmaf(zs[t*64+p], vs[t*64+qq], sp);
    spv[k] = sp; l1 += sp; l2 += sp*sp;
  }
  float tot0, tot1;
  {
    float val = wsum(l1);
    if ((tid & 63) == 0) red[tid >> 6] = val;
    __syncthreads();
    tot0 = red[0] + red[1] + red[2] + red[3];
    __syncthreads();
    val = wsum(l2);
    if ((tid & 63) == 0) red[tid >> 6] = val;
    __syncthreads();
    tot1 = red[0] + red[1] + red[2] + red[3];
  }
  float mP = tot0 * (1.f/4096.f);
  float varP = tot1 * (1.f/4096.f) - mP*mP;
  float invv = rsqrtf(varP + 1e-5f);
  if (path == 0){
    if (tid == 0) mps2[b] = varP * invv * invv;  // E[PsL^2]
    if (tid < 64){
      int d = tid;
      float zc = 0.f;
#pragma unroll
      for (int t = 0; t < 8; t++) zc += zs[t*64+d];
      float s1 = wsum(zc), s2 = wsum(zc*zc);
      float mz = s1*(1.f/64.f), vz = s2*(1.f/64.f) - mz*mz;
      PzL[b*64+d] = (zc - mz) * rsqrtf(vz + 1e-5f);
    }
#pragma unroll
    for (int k = 0; k < 16; k++){
      int o = p*64 + q0 + k;
      PsL[b*4096 + o] = (spv[k] - mP) * invv;
    }
  } else {
    int u = uid[b];
    if (tid < 64){
      int d = tid;
      float zc = 0.f;
#pragma unroll
      for (int t = 0; t < 8; t++) zc += zs[t*64+d];
      float s1 = wsum(zc), s2 = wsum(zc*zc);
      float mz = s1*(1.f/64.f), vz = s2*(1.f/64.f) - mz*mz;
      float szl = (zc - mz) * rsqrtf(vz + 1e-5f);
      float pzv = prev_z[u*64 + d];
      float zu = pzv + szl;
      float zl2 = wsum(zu*zu);
      float psumv = wsum(pzv);
      float fac = ((psumv != 0.f) ? 1.f : 0.f) / (sqrtf(zl2) + 1e-8f);
      if (d == 0) facs = fac;
    }
    __syncthreads();
    float fac = facs;
    const float* psrow = prev_s + (size_t)u * 4096;
#pragma unroll
    for (int k = 0; k < 16; k++){
      int o = p*64 + q0 + k;
      pNAM[b*4096 + o] = (psrow[o] + (spv[k] - mP) * invv) * fac;
    }
  }
}

// K3a: fused 64x64-tile Gram + Score + AV. Grid = B*10 (pairs rt>=ct over 4 row-tiles).
// All LDS tiles transposed [k][*] stride 64; 5 x 16KB = 80KiB exactly -> 2 blocks/CU.
__global__ __launch_bounds__(256) void k_gram64(const float* __restrict__ z, const float* __restrict__ v,
    const float* __restrict__ nq,
    float* __restrict__ colpart, float* __restrict__ harr, float* __restrict__ NAP){
  __shared__ float smem[20480];
  float* zlT = smem;           // [k][r]
  float* vlT = smem + 4096;
  float* nlT = smem + 8192;    // reused as scsT [c][r] after main phase
  float* ztT = smem + 12288;   // [k][c]
  float* vtT = smem + 16384;
  int bid = blockIdx.x;
  int b = bid / 10, pi = bid % 10;
  int rt, ct;
  if (pi < 1){ rt = 0; ct = 0; }
  else if (pi < 3){ rt = 1; ct = pi - 1; }
  else if (pi < 6){ rt = 2; ct = pi - 3; }
  else { rt = 3; ct = pi - 6; }
  int l0 = rt*64, t0 = ct*64;
  int tid = threadIdx.x;
  const float* zb = z + b*12800;
  const float* vb = v + b*12800;
  const float* nb = nq + b*12800;
  // stage (transposed scalar writes, 2-way conflict = free)
  {
    int r = tid & 63, kq = tid >> 6;
    int l = l0 + r, t = t0 + r;
    bool lv = l < L_, tv = t < L_;
#pragma unroll
    for (int m = 0; m < 4; m++){
      int k0 = kq*16 + m*4;
      float4 zr4 = lv ? *(const float4*)(zb + l*64 + k0) : make_float4(0,0,0,0);
      float4 vr4 = lv ? *(const float4*)(vb + l*64 + k0) : make_float4(0,0,0,0);
      float4 nr4 = lv ? *(const float4*)(nb + l*64 + k0) : make_float4(0,0,0,0);
      float4 zc4 = tv ? *(const float4*)(zb + t*64 + k0) : make_float4(0,0,0,0);
      float4 vc4 = tv ? *(const float4*)(vb + t*64 + k0) : make_float4(0,0,0,0);
      zlT[(k0+0)*64+r]=zr4.x; zlT[(k0+1)*64+r]=zr4.y; zlT[(k0+2)*64+r]=zr4.z; zlT[(k0+3)*64+r]=zr4.w;
      vlT[(k0+0)*64+r]=vr4.x; vlT[(k0+1)*64+r]=vr4.y; vlT[(k0+2)*64+r]=vr4.z; vlT[(k0+3)*64+r]=vr4.w;
      nlT[(k0+0)*64+r]=nr4.x; nlT[(k0+1)*64+r]=nr4.y; nlT[(k0+2)*64+r]=nr4.z; nlT[(k0+3)*64+r]=nr4.w;
      ztT[(k0+0)*64+r]=zc4.x; ztT[(k0+1)*64+r]=zc4.y; ztT[(k0+2)*64+r]=zc4.z; ztT[(k0+3)*64+r]=zc4.w;
      vtT[(k0+0)*64+r]=vc4.x; vtT[(k0+1)*64+r]=vc4.y; vtT[(k0+2)*64+r]=vc4.z; vtT[(k0+3)*64+r]=vc4.w;
    }
  }
  __syncthreads();
  int rg = tid >> 4, cg = tid & 15;
  int r0 = rg*4, c0 = cg*4;
  float az[16], av[16], an[16];
#pragma unroll
  for (int i = 0; i < 16; i++){ az[i]=0.f; av[i]=0.f; an[i]=0.f; }
  for (int k = 0; k < 64; k++){
    float4 zr4 = *(const float4*)&zlT[k*64 + r0];
    float4 vr4 = *(const float4*)&vlT[k*64 + r0];
    float4 nr4 = *(const float4*)&nlT[k*64 + r0];
    float4 zc4 = *(const float4*)&ztT[k*64 + c0];
    float4 vc4 = *(const float4*)&vtT[k*64 + c0];
    float zr[4] = {zr4.x, zr4.y, zr4.z, zr4.w};
    float vr[4] = {vr4.x, vr4.y, vr4.z, vr4.w};
    float nr[4] = {nr4.x, nr4.y, nr4.z, nr4.w};
    float zc[4] = {zc4.x, zc4.y, zc4.z, zc4.w};
    float vc[4] = {vc4.x, vc4.y, vc4.z, vc4.w};
#pragma unroll
    for (int i = 0; i < 4; i++){
#pragma unroll
      for (int j = 0; j < 4; j++){
        az[i*4+j] = fmaf(zr[i], zc[j], az[i*4+j]);
        av[i*4+j] = fmaf(vr[i], vc[j], av[i*4+j]);
        an[i*4+j] = fmaf(nr[i], zc[j], an[i*4+j]);
      }
    }
  }
  bool diag = (rt == ct);
  // colsum partials per row (reduce over 16 col-lanes)
  float prow[4];
#pragma unroll
  for (int i = 0; i < 4; i++){
    float s = 0.f;
#pragma unroll
    for (int j = 0; j < 4; j++){
      bool keep = !diag || (c0 + j <= r0 + i);
      if (keep) s += az[i*4+j] * av[i*4+j];
    }
    prow[i] = s;
  }
#pragma unroll
  for (int o = 1; o < 16; o <<= 1){
#pragma unroll
    for (int i = 0; i < 4; i++) prow[i] += __shfl_xor(prow[i], o, 64);
  }
  if (cg == 0){
#pragma unroll
    for (int i = 0; i < 4; i++){
      int l = l0 + r0 + i;
      if (l < L_) colpart[(b*L_ + l)*4 + ct] = prow[i];
    }
  }
  if (diag && rg == cg){
#pragma unroll
    for (int i = 0; i < 4; i++){
      int l = l0 + r0 + i;
      if (l < L_) harr[b*L_ + l] = az[i*4+i] * av[i*4+i];
    }
  }
  __syncthreads();   // main-phase nlT reads complete; reuse as scsT
  float* scsT = nlT;
#pragma unroll
  for (int j = 0; j < 4; j++){
    int c = c0 + j;
    float m0 = (!diag || c <= r0+0) ? an[0*4+j] : 0.f;
    float m1 = (!diag || c <= r0+1) ? an[1*4+j] : 0.f;
    float m2 = (!diag || c <= r0+2) ? an[2*4+j] : 0.f;
    float m3 = (!diag || c <= r0+3) ? an[3*4+j] : 0.f;
    *(float4*)&scsT[c*64 + r0] = make_float4(m0, m1, m2, m3);
  }
  __syncthreads();
  // AV: out[r][d] = sum_c scsT[c][r] * v[t0+c][d]  (V from L2, scs from LDS)
  int d0 = c0;
  float o4[16];
#pragma unroll
  for (int i = 0; i < 16; i++) o4[i] = 0.f;
#pragma unroll 2
  for (int c = 0; c < 64; c++){
    float4 s4 = *(const float4*)&scsT[c*64 + r0];
    int t = t0 + c; if (t > L_-1) t = L_-1;   // masked scs==0 for t>=L_
    float4 v4 = *(const float4*)(vb + t*64 + d0);
    float sv[4] = {s4.x, s4.y, s4.z, s4.w};
    float vv[4] = {v4.x, v4.y, v4.z, v4.w};
#pragma unroll
    for (int i = 0; i < 4; i++){
#pragma unroll
      for (int j = 0; j < 4; j++) o4[i*4+j] = fmaf(sv[i], vv[j], o4[i*4+j]);
    }
  }
  float* nap = NAP + ((size_t)((b*4 + rt)*4 + ct))*4096;
#pragma unroll
  for (int i = 0; i < 4; i++)
    *(float4*)&nap[(r0+i)*64 + d0] = make_float4(o4[i*4+0], o4[i*4+1], o4[i*4+2], o4[i*4+3]);
}

// K3b: T1 = NQ.PsL, T2 = NQ.pNAM, carr = z^T PsL v. Grid B*7 (32-row tiles).
#define PADK 68
__global__ __launch_bounds__(256) void k_t12(const float* __restrict__ z, const float* __restrict__ v,
    const float* __restrict__ nq, const float* __restrict__ PsL, const float* __restrict__ pNAM,
    float* __restrict__ carr, float* __restrict__ T1, float* __restrict__ T2){
  int b = blockIdx.x / 7, rtile = blockIdx.x % 7;
  int l0 = rtile * 32;
  int tid = threadIdx.x;
  __shared__ float zl[32*PADK], vl[32*PADK];
  __shared__ float nqt[32*65];
  for (int k = tid; k < 2048; k += 256){
    int r = k >> 6, d = k & 63, lr = l0 + r;
    bool ok = lr < L_;
    zl[r*PADK+d]  = ok ? z[(b*L_+lr)*64 + d] : 0.f;
    vl[r*PADK+d]  = ok ? v[(b*L_+lr)*64 + d] : 0.f;
    nqt[r*65+d]   = ok ? nq[(b*L_+lr)*64 + d] : 0.f;
  }
  __syncthreads();
  // carr
  {
    int w = tid >> 6, lane = tid & 63;
    float wacc[8] = {0,0,0,0,0,0,0,0};
    const float* psb = PsL + b*4096 + lane*64;
    for (int qq = 0; qq < 64; qq += 4){
      float4 p4 = *(const float4*)(psb + qq);
#pragma unroll
      for (int r8 = 0; r8 < 8; r8++){
        float4 v4 = *(const float4*)&vl[(w*8+r8)*PADK+qq];
        wacc[r8] += p4.x*v4.x + p4.y*v4.y + p4.z*v4.z + p4.w*v4.w;
      }
    }
#pragma unroll
    for (int r8 = 0; r8 < 8; r8++){
      int rr = w*8 + r8, l = l0 + rr;
      float c = wsum(zl[rr*PADK+lane] * wacc[r8]);
      if (lane == 0 && l < L_) carr[b*L_ + l] = c;
    }
  }
  // T1/T2
  int r = tid & 31, c8 = tid >> 5, c0 = c8 * 8;
  float t1a[8] = {0,0,0,0,0,0,0,0}, t2a[8] = {0,0,0,0,0,0,0,0};
  const float* psm = PsL + b*4096;
  const float* pnm = pNAM + b*4096;
  for (int pp = 0; pp < 64; pp++){
    float nv = nqt[r*65 + pp];
    float4 a0 = *(const float4*)(psm + pp*64 + c0);
    float4 a1 = *(const float4*)(psm + pp*64 + c0 + 4);
    float4 b0 = *(const float4*)(pnm + pp*64 + c0);
    float4 b1 = *(const float4*)(pnm + pp*64 + c0 + 4);
    t1a[0] = fmaf(nv, a0.x, t1a[0]); t1a[1] = fmaf(nv, a0.y, t1a[1]);
    t1a[2] = fmaf(nv, a0.z, t1a[2]); t1a[3] = fmaf(nv, a0.w, t1a[3]);
    t1a[4] = fmaf(nv, a1.x, t1a[4]); t1a[5] = fmaf(nv, a1.y, t1a[5]);
    t1a[6] = fmaf(nv, a1.z, t1a[6]); t1a[7] = fmaf(nv, a1.w, t1a[7]);
    t2a[0] = fmaf(nv, b0.x, t2a[0]); t2a[1] = fmaf(nv, b0.y, t2a[1]);
    t2a[2] = fmaf(nv, b0.z, t2a[2]); t2a[3] = fmaf(nv, b0.w, t2a[3]);
    t2a[4] = fmaf(nv, b1.x, t2a[4]); t2a[5] = fmaf(nv, b1.y, t2a[5]);
    t2a[6] = fmaf(nv, b1.z, t2a[6]); t2a[7] = fmaf(nv, b1.w, t2a[7]);
  }
  int l = l0 + r;
  if (l < L_){
    float* t1p = T1 + (b*L_+l)*64 + c0;
    float* t2p = T2 + (b*L_+l)*64 + c0;
    *(float4*)(t1p)     = make_float4(t1a[0], t1a[1], t1a[2], t1a[3]);
    *(float4*)(t1p + 4) = make_float4(t1a[4], t1a[5], t1a[6], t1a[7]);
    *(float4*)(t2p)     = make_float4(t2a[0], t2a[1], t2a[2], t2a[3]);
    *(float4*)(t2p + 4) = make_float4(t2a[4], t2a[5], t2a[6], t2a[7]);
  }
}

// K3c: per-b prefix sums: Zcum + 3 scalar scans (shfl-based)
__global__ __launch_bounds__(64) void k_cumsum(const float* __restrict__ z,
    const float* __restrict__ sz, const float* __restrict__ sv,
    const float* __restrict__ colpart, const float* __restrict__ harr, const float* __restrict__ carr,
    float* __restrict__ Zcum, float* __restrict__ cM, float* __restrict__ cR, float* __restrict__ cC){
  int b = blockIdx.x, lane = threadIdx.x;
  const float* zb = z + b*12800;
  float* Zb = Zcum + b*12800;
  float Zc = 0.f;
  for (int l = 0; l < 200; l += 4){
    float a0 = zb[(l+0)*64+lane];
    float a1 = zb[(l+1)*64+lane];
    float a2 = zb[(l+2)*64+lane];
    float a3 = zb[(l+3)*64+lane];
    Zc += a0; Zb[(l+0)*64+lane] = Zc;
    Zc += a1; Zb[(l+1)*64+lane] = Zc;
    Zc += a2; Zb[(l+2)*64+lane] = Zc;
    Zc += a3; Zb[(l+3)*64+lane] = Zc;
  }
  float carryM = 0.f, carryR = 0.f, carryC = 0.f;
#pragma unroll
  for (int c = 0; c < 4; c++){
    int l = c*64 + lane;
    bool valid = l < 200;
    int row = b*200 + l;
    float tcol = 0.f;
    if (valid){
      int ltile = l >> 6;
#pragma unroll
      for (int j = 0; j < 4; j++)
        if (j <= ltile) tcol += colpart[row*4 + j];
    }
    float tm = valid ? sz[row]*sv[row] : 0.f;
    float tr = valid ? 2.f*tcol - harr[row] : 0.f;
    float tc = valid ? carr[row] : 0.f;
#pragma unroll
    for (int o = 1; o < 64; o <<= 1){
      float y0 = __shfl_up(tm, o, 64);
      float y1 = __shfl_up(tr, o, 64);
      float y2 = __shfl_up(tc, o, 64);
      if (lane >= o){ tm += y0; tr += y1; tc += y2; }
    }
    tm += carryM; tr += carryR; tc += carryC;
    if (valid){ cM[row] = tm; cR[row] = tr; cC[row] = tc; }
    carryM = __shfl(tm, 63, 64);
    carryR = __shfl(tr, 63, 64);
    carryC = __shfl(tc, 63, 64);
  }
}

// K4: per (b,l), 64 thr: reduce NAP partials + coefficients + final LN + std partials
__global__ __launch_bounds__(64) void k_finred(const float* __restrict__ q, const float* __restrict__ Zcum,
    const float* __restrict__ PzL, const float* __restrict__ mps2, const float* __restrict__ snq,
    const float* __restrict__ cM, const float* __restrict__ cR, const float* __restrict__ cC,
    const float* __restrict__ T1, const float* __restrict__ T2, const float* __restrict__ NAP,
    float* __restrict__ out, float* __restrict__ Syr, float* __restrict__ Sy2r){
  int row = blockIdx.x;
  int b = row / 200, l = row % 200;
  int lane = threadIdx.x;
  int rt = l >> 6, r = l & 63;
  const float* np_ = NAP + ((size_t)((b*4 + rt)*4))*4096 + r*64 + lane;
  float acc = 0.f;
  for (int ct = 0; ct <= rt; ct++) acc += np_[ct*4096];
  float zc = Zcum[row*64 + lane];
  float s1 = wsum(zc), s2 = wsum(zc*zc);
  float mz = s1*(1.f/64.f), vz = s2*(1.f/64.f) - mz*mz;
  float zf = (zc - mz) * rsqrtf(vz + 1e-5f) + PzL[b*64 + lane];
  float zl2 = wsum(zf*zf);
  float a = sqrtf(zl2) + 1e-8f;
  float m = cM[row] * (1.f/4096.f);
  float var = cR[row] * (1.f/4096.f) - m*m;
  float inv = rsqrtf(var + 1e-5f);
  float varT = inv*inv*var + 2.f*inv*cC[row]*(1.f/4096.f) + mps2[b];
  float invT = rsqrtf(varT + 1e-5f*a*a);
  float cAv = invT*inv;
  float cBv = invT*inv*m*snq[row];
  float cCv = invT;
  float y = q[row*64 + lane] / fmaxf(zf, 1e-6f);
  float ys = wsum(y), ys2 = wsum(y*y);
  if (lane == 0){ Syr[row] = ys; Sy2r[row] = ys2; }
  float NA1 = cAv*acc - cBv + cCv*T1[row*64 + lane] + T2[row*64 + lane];
  float r1 = wsum(NA1), r2 = wsum(NA1*NA1);
  float mm = r1*(1.f/64.f), vv = r2*(1.f/64.f) - mm*mm;
  out[row*64 + lane] = (NA1 - mm) * rsqrtf(vv + 1e-5f);
}

// K5: finalize std (ddof=1); reduce 6400 row partials
__global__ __launch_bounds__(256) void k_std(const float* __restrict__ Syr, const float* __restrict__ Sy2r,
    float* __restrict__ out){
  __shared__ float redA[4], redB[4];
  int tid = threadIdx.x, lane = tid & 63, g = tid >> 6;
  float a = 0.f, b2 = 0.f;
  for (int i = tid; i < 6400; i += 256){ a += Syr[i]; b2 += Sy2r[i]; }
  a = wsum(a); b2 = wsum(b2);
  if (lane == 0){ redA[g] = a; redB[g] = b2; }
  __syncthreads();
  if (tid == 0){
    float A = redA[0]+redA[1]+redA[2]+redA[3];
    float B2 = redB[0]+redB[1]+redB[2]+redB[3];
    const float N = 409600.f;
    float var = (B2 - A*A/N) / (N - 1.f);
    out[409600] = sqrtf(fmaxf(var, 0.f));
  }
}

extern "C" void kernel_launch(void* const* d_in, const int* in_sizes, int n_in,
                              void* d_out, int out_size, void* d_ws, size_t ws_size,
                              hipStream_t stream) {
  const int*   uid    = (const int*)d_in[0];
  const float* seqs   = (const float*)d_in[1];
  const float* P      = (const float*)d_in[2];
  const float* S      = (const float*)d_in[3];
  const float* prev_z = (const float*)d_in[4];
  const float* prev_s = (const float*)d_in[5];
  const float* Wq     = (const float*)d_in[6];
  const float* bq     = (const float*)d_in[7];
  const float* Wk     = (const float*)d_in[8];
  const float* bk     = (const float*)d_in[9];
  const float* Wv     = (const float*)d_in[10];
  const float* bv     = (const float*)d_in[11];
  float* w   = (float*)d_ws;
  float* out = (float*)d_out;

  k_transpose<<<192, 256, 0, stream>>>(Wq, Wk, Wv, w + OFF_WT);
  k_qzv<<<400, 256, 0, stream>>>(seqs, w + OFF_WT, bq, bk, bv,
      w + OFF_Q, w + OFF_NQ, w + OFF_Z, w + OFF_V, w + OFF_SZ, w + OFF_SV, w + OFF_SNQ);
  k_prompt<<<64, 256, 0, stream>>>(P, S, uid, prev_z, prev_s, w + OFF_WT, bk, bv,
      w + OFF_PZL, w + OFF_PSL, w + OFF_MPS2, w + OFF_PNAM);
  k_gram64<<<B_*10, 256, 0, stream>>>(w + OFF_Z, w + OFF_V, w + OFF_NQ,
      w + OFF_CP, w + OFF_H, w + OFF_NAP);
  k_t12<<<B_*7, 256, 0, stream>>>(w + OFF_Z, w + OFF_V, w + OFF_NQ,
      w + OFF_PSL, w + OFF_PNAM,
      w + OFF_C, w + OFF_T1, w + OFF_T2);
  k_cumsum<<<32, 64, 0, stream>>>(w + OFF_Z, w + OFF_SZ, w + OFF_SV,
      w + OFF_CP, w + OFF_H, w + OFF_C,
      w + OFF_ZC, w + OFF_CM, w + OFF_CR, w + OFF_CCP);
  k_finred<<<6400, 64, 0, stream>>>(w + OFF_Q, w + OFF_ZC,
      w + OFF_PZL, w + OFF_MPS2, w + OFF_SNQ,
      w + OFF_CM, w + OFF_CR, w + OFF_CCP,
      w + OFF_T1, w + OFF_T2, w + OFF_NAP,
      out, w + OFF_SYR, w + OFF_SY2R);
  k_std<<<1, 256, 0, stream>>>(w + OFF_SYR, w + OFF_SY2R, out);
}